// Round 7
// baseline (552.276 us; speedup 1.0000x reference)
//
#include <hip/hip_runtime.h>
#include <hip/hip_fp16.h>

#define NN 100000
#define EE 1600000
#define HH 128
#define GG 64
#define CC 32
#define ETOT (EE + NN)   // edges + self-loops

// bucketed-partition params
#define NB 256                      // dst buckets
#define BS 392                      // nodes per bucket (256*392 >= 100000)
#define CHUNK 8192                  // edges per partition block
#define NBLK ((EE + CHUNK - 1) / CHUNK)   // 196
#define MATL (NB * NBLK)            // 50176

typedef _Float16 half8 __attribute__((ext_vector_type(8)));
typedef float f32x4 __attribute__((ext_vector_type(4)));

// ---------------- init: zero pool accumulators + t16 zero-row (row NN) ----------------
__global__ void k_init(float* __restrict__ pooled, float* __restrict__ gcnt, __half* __restrict__ t16) {
    int i = blockIdx.x * blockDim.x + threadIdx.x;
    if (i < GG * HH) pooled[i] = 0.f;
    if (i < GG) gcnt[i] = 0.f;
    if (i < HH) t16[(size_t)NN * HH + i] = __float2half(0.f);
}

// ---------------- W[k][n] fp32 -> Wt[n][k] fp16 (3 layers) ----------------
__global__ __launch_bounds__(256) void k_prepw(const float* __restrict__ W1, const float* __restrict__ W2,
                                               const float* __restrict__ W3, __half* __restrict__ wt) {
    __shared__ float sW[HH * (HH + 1)];
    const float* W = (blockIdx.x == 0) ? W1 : (blockIdx.x == 1) ? W2 : W3;
    __half* out = wt + (size_t)blockIdx.x * HH * HH;
    int t = threadIdx.x;
    #pragma unroll 4
    for (int i = 0; i < 64; i++) {
        int idx = i * 256 + t;
        sW[(idx >> 7) * (HH + 1) + (idx & 127)] = W[idx];
    }
    __syncthreads();
    #pragma unroll 4
    for (int i = 0; i < 64; i++) {
        int o = i * 256 + t;
        int n = o >> 7, k = o & 127;
        out[o] = __float2half(sW[k * (HH + 1) + n]);
    }
}

// ---------------- single-block exclusive scan (L up to ~100K) ----------------
__global__ __launch_bounds__(1024) void k_scan1(const int* __restrict__ in, int* __restrict__ off,
                                                int L, int total) {
    __shared__ int s[1024];
    int t = threadIdx.x;
    int CH = (L + 1023) >> 10;
    int beg = t * CH;
    int end = beg + CH; if (end > L) end = L;
    int sum = 0;
    for (int i = beg; i < end; i++) sum += in[i];
    s[t] = sum;
    __syncthreads();
    for (int o = 1; o < 1024; o <<= 1) {
        int tmp = (t >= o) ? s[t - o] : 0;
        __syncthreads();
        s[t] += tmp;
        __syncthreads();
    }
    int base = s[t] - sum;       // exclusive prefix of this segment
    for (int i = beg; i < end; i++) { off[i] = base; base += in[i]; }
    if (t == 0) off[L] = total;
}

// ---------------- phase A1: per-block bucket histogram -> mat[bucket][block] ----------------
__global__ __launch_bounds__(256) void k_hist(const int* __restrict__ dst, int* __restrict__ mat) {
    __shared__ int hist[NB];
    int t = threadIdx.x, blk = blockIdx.x;
    hist[t] = 0;
    __syncthreads();
    int base = blk * CHUNK;
    #pragma unroll 4
    for (int it = 0; it < CHUNK / 256; it++) {
        int e = base + it * 256 + t;
        if (e < EE) atomicAdd(&hist[dst[e] / BS], 1);
    }
    __syncthreads();
    mat[t * NBLK + blk] = hist[t];
}

// ---------------- phase A2: scatter edges into per-(block,bucket) runs ----------------
__global__ __launch_bounds__(256) void k_binscatter(const int* __restrict__ src, const int* __restrict__ dst,
                                                    const int* __restrict__ matscan, int* __restrict__ staged) {
    __shared__ int lcur[NB];
    int t = threadIdx.x, blk = blockIdx.x;
    lcur[t] = matscan[t * NBLK + blk];
    __syncthreads();
    int base = blk * CHUNK;
    #pragma unroll 4
    for (int it = 0; it < CHUNK / 256; it++) {
        int e = base + it * 256 + t;
        if (e < EE) {
            int d = dst[e], s = src[e];
            int b = d / BS;
            int pos = atomicAdd(&lcur[b], 1);
            staged[pos] = s | ((d - b * BS) << 17);     // src 17b | dst_local 9b
        }
    }
}

// ---------------- phase B1: per-bucket degree counts (incl self) + dinv ----------------
__global__ __launch_bounds__(256) void k_bcount(const int* __restrict__ matscan, const int* __restrict__ staged,
                                                int* __restrict__ counts, float* __restrict__ dinv) {
    __shared__ int cnt[BS];
    int t = threadIdx.x, b = blockIdx.x;
    for (int i = t; i < BS; i += 256) cnt[i] = 1;       // self-loop
    __syncthreads();
    int beg = matscan[b * NBLK], end = matscan[(b + 1) * NBLK];
    for (int p = beg + t; p < end; p += 256) atomicAdd(&cnt[staged[p] >> 17], 1);
    __syncthreads();
    int nb0 = b * BS;
    for (int i = t; i < BS; i += 256) {
        int n = nb0 + i;
        if (n < NN) { int c = cnt[i]; counts[n] = c; dinv[n] = rsqrtf((float)c); }
    }
}

// ---------------- phase B2: place edges into CSR (L2-local per bucket) ----------------
__global__ __launch_bounds__(256) void k_place(const int* __restrict__ matscan, const int* __restrict__ staged,
                                               const int* __restrict__ row_off, int* __restrict__ csr_src) {
    __shared__ int rof[BS];
    __shared__ int lcur[BS];
    int t = threadIdx.x, b = blockIdx.x;
    int nb0 = b * BS;
    for (int i = t; i < BS; i += 256) {
        int n = nb0 + i;
        int r = (n < NN) ? row_off[n] : 0;
        rof[i] = r; lcur[i] = 1;
        if (n < NN) csr_src[r] = n;                     // self edge in slot 0
    }
    __syncthreads();
    int beg = matscan[b * NBLK], end = matscan[(b + 1) * NBLK];
    for (int p = beg + t; p < end; p += 256) {
        int pk = staged[p];
        int dl = pk >> 17, s = pk & 0x1FFFF;
        int pos = rof[dl] + atomicAdd(&lcur[dl], 1);
        csr_src[pos] = s;
    }
}

// ---------------- MFMA GEMM: T[r][c](fp16) = dinv[r] * (A[r][:] @ W)[c] ----------------
// F32IN: A is fp32 (layer 1, converts during staging); else fp16.
template<int F32IN>
__global__ __launch_bounds__(256) void k_gemm(const void* __restrict__ Ap, const __half* __restrict__ Wt,
                                              const float* __restrict__ dinv, __half* __restrict__ T) {
    __shared__ __align__(16) char sm[64 * 1024];
    char* sA = sm;                 // 128 rows x 256B fp16, XOR-swizzled
    char* sB = sm + 32 * 1024;
    int tid = threadIdx.x;
    int r0 = blockIdx.x * 128;

    #pragma unroll
    for (int it = 0; it < 8; it++) {
        int p = (tid + it * 256) * 16;            // LDS byte (fp16 tile)
        int lrow = p >> 8;
        int grow = r0 + lrow; if (grow > NN - 1) grow = NN - 1;
        uint4 v;
        if (F32IN) {
            const char* Ab = (const char*)Ap;
            const float4* f0 = (const float4*)(Ab + (size_t)grow * 512 + (p & 255) * 2);
            float4 a = f0[0], b = f0[1];
            union { uint4 u; __half2 h[4]; } pk;
            pk.h[0] = __floats2half2_rn(a.x, a.y);
            pk.h[1] = __floats2half2_rn(a.z, a.w);
            pk.h[2] = __floats2half2_rn(b.x, b.y);
            pk.h[3] = __floats2half2_rn(b.z, b.w);
            v = pk.u;
        } else {
            const char* Ab = (const char*)Ap;
            v = *(const uint4*)(Ab + (size_t)grow * 256 + (p & 255));
        }
        *(uint4*)(sA + (p ^ ((lrow & 7) << 4))) = v;
    }
    const char* Wb = (const char*)Wt;
    #pragma unroll
    for (int it = 0; it < 8; it++) {
        int p = (tid + it * 256) * 16;
        int lrow = p >> 8;
        uint4 v = *(const uint4*)(Wb + p);
        *(uint4*)(sB + (p ^ ((lrow & 7) << 4))) = v;
    }
    __syncthreads();

    int w = tid >> 6;
    int lane = tid & 63;
    int q = lane >> 4;
    int ln = lane & 15;
    int wr = (w >> 1) * 64;
    int wc = (w & 1) * 64;

    f32x4 acc[4][4];
    #pragma unroll
    for (int a = 0; a < 4; a++)
        #pragma unroll
        for (int b = 0; b < 4; b++) acc[a][b] = (f32x4)0.f;

    #pragma unroll
    for (int ks = 0; ks < 4; ks++) {
        int koff = ks * 64 + q * 16;
        half8 af[4], bf[4];
        #pragma unroll
        for (int mi = 0; mi < 4; mi++) {
            int row = wr + mi * 16 + ln;
            af[mi] = *(half8*)(sA + row * 256 + (koff ^ ((row & 7) << 4)));
        }
        #pragma unroll
        for (int ni = 0; ni < 4; ni++) {
            int row = wc + ni * 16 + ln;
            bf[ni] = *(half8*)(sB + row * 256 + (koff ^ ((row & 7) << 4)));
        }
        #pragma unroll
        for (int mi = 0; mi < 4; mi++)
            #pragma unroll
            for (int ni = 0; ni < 4; ni++)
                acc[mi][ni] = __builtin_amdgcn_mfma_f32_16x16x32_f16(af[mi], bf[ni], acc[mi][ni], 0, 0, 0);
    }

    float dv[4][4];
    #pragma unroll
    for (int mi = 0; mi < 4; mi++)
        #pragma unroll
        for (int r = 0; r < 4; r++) {
            int grow = r0 + wr + mi * 16 + q * 4 + r;
            dv[mi][r] = dinv[grow < NN ? grow : 0];
        }
    #pragma unroll
    for (int mi = 0; mi < 4; mi++) {
        #pragma unroll
        for (int r = 0; r < 4; r++) {
            int grow = r0 + wr + mi * 16 + q * 4 + r;
            if (grow < NN) {
                #pragma unroll
                for (int ni = 0; ni < 4; ni++) {
                    int gcol = wc + ni * 16 + ln;
                    T[(size_t)grow * HH + gcol] = __float2half(acc[mi][ni][r] * dv[mi][r]);
                }
            }
        }
    }
}

// ---------------- aggregation: O[n] = relu?( dinv[n]*sum_{csr} T'[src] + bias ) ----------------
// 4 edges/wave-iter; packed fp16 accumulate (v_pk_add_f16); zero-row NN for invalid slots.
__global__ __launch_bounds__(256) void k_agg(const __half* __restrict__ T, __half* __restrict__ O,
                                             const int* __restrict__ row_off, const int* __restrict__ csr_src,
                                             const float* __restrict__ dinv,
                                             const float* __restrict__ bias, int relu) {
    int gt = blockIdx.x * blockDim.x + threadIdx.x;
    int n = gt >> 6;
    if (n >= NN) return;
    int lane = threadIdx.x & 63;
    int g  = lane >> 4;
    int li = lane & 15;

    int beg = row_off[n], end = row_off[n + 1];
    int nit = (end - beg + 3) >> 2;

    __half2 acch[4];
    #pragma unroll
    for (int c = 0; c < 4; c++) acch[c] = __floats2half2_rn(0.f, 0.f);

    int p = beg + g;
    const char* Tb = (const char*)T;
    #pragma unroll 4
    for (int i = 0; i < nit; i++, p += 4) {
        int sraw = csr_src[p];                        // csr_src padded by 8 ints
        int s = (p < end) ? sraw : NN;                // zero row for invalid slots
        uint4 raw = *(const uint4*)(Tb + (((unsigned)s << 8) | ((unsigned)li << 4)));
        const __half2* hp = (const __half2*)&raw;
        acch[0] = __hadd2(acch[0], hp[0]);
        acch[1] = __hadd2(acch[1], hp[1]);
        acch[2] = __hadd2(acch[2], hp[2]);
        acch[3] = __hadd2(acch[3], hp[3]);
    }

    // cross-slot reduce in fp16 (lanes l, l^16, l^32, l^48)
    #pragma unroll
    for (int c = 0; c < 4; c++) {
        union { __half2 h; int i; } u, v;
        u.h = acch[c];
        v.i = __shfl_xor(u.i, 16, 64);
        u.h = __hadd2(u.h, v.h);
        v.i = __shfl_xor(u.i, 32, 64);
        u.h = __hadd2(u.h, v.h);
        acch[c] = u.h;
    }

    if (g == 0) {
        float dn = dinv[n];
        float2 f0 = __half22float2(acch[0]);
        float2 f1 = __half22float2(acch[1]);
        float2 f2 = __half22float2(acch[2]);
        float2 f3 = __half22float2(acch[3]);
        const float4* B4 = (const float4*)bias;
        float4 b0 = B4[li * 2], b1 = B4[li * 2 + 1];
        float o0 = dn * f0.x + b0.x, o1 = dn * f0.y + b0.y;
        float o2 = dn * f1.x + b0.z, o3 = dn * f1.y + b0.w;
        float o4 = dn * f2.x + b1.x, o5 = dn * f2.y + b1.y;
        float o6 = dn * f3.x + b1.z, o7 = dn * f3.y + b1.w;
        if (relu) {
            o0 = fmaxf(o0, 0.f); o1 = fmaxf(o1, 0.f); o2 = fmaxf(o2, 0.f); o3 = fmaxf(o3, 0.f);
            o4 = fmaxf(o4, 0.f); o5 = fmaxf(o5, 0.f); o6 = fmaxf(o6, 0.f); o7 = fmaxf(o7, 0.f);
        }
        union { uint4 u; __half2 h2[4]; } pk;
        pk.h2[0] = __floats2half2_rn(o0, o1);
        pk.h2[1] = __floats2half2_rn(o2, o3);
        pk.h2[2] = __floats2half2_rn(o4, o5);
        pk.h2[3] = __floats2half2_rn(o6, o7);
        *(uint4*)(O + (size_t)n * HH + li * 8) = pk.u;
    }
}

// ---------------- pooling: batch sorted -> run-length accumulate (fp16 in) ----------------
__global__ __launch_bounds__(128) void k_pool(const __half* __restrict__ Hm, const int* __restrict__ batch,
                                              float* __restrict__ pooled, float* __restrict__ gcnt) {
    int j = threadIdx.x;
    int n0 = blockIdx.x * 64;
    int nend = n0 + 64; if (nend > NN) nend = NN;
    float acc = 0.f;
    int gcur = batch[n0];
    int run = 0;
    for (int n = n0; n < nend; n++) {
        int g = batch[n];
        if (g != gcur) {
            atomicAdd(&pooled[gcur * HH + j], acc);
            if (j == 0) atomicAdd(&gcnt[gcur], (float)run);
            acc = 0.f; run = 0; gcur = g;
        }
        acc += __half2float(Hm[(size_t)n * HH + j]);
        run++;
    }
    atomicAdd(&pooled[gcur * HH + j], acc);
    if (j == 0) atomicAdd(&gcnt[gcur], (float)run);
}

// ---------------- classifier ----------------
__global__ void k_classify(const float* __restrict__ pooled, const float* __restrict__ gcnt,
                           const float* __restrict__ Wc, const float* __restrict__ bc,
                           float* __restrict__ out) {
    int idx = blockIdx.x * blockDim.x + threadIdx.x;
    if (idx >= GG * CC) return;
    int g = idx >> 5, c = idx & 31;
    float inv = 1.f / fmaxf(gcnt[g], 1.f);
    float acc = bc[c];
    for (int k = 0; k < HH; k++) acc += pooled[g * HH + k] * inv * Wc[k * CC + c];
    out[idx] = acc;
}

extern "C" void kernel_launch(void* const* d_in, const int* in_sizes, int n_in,
                              void* d_out, int out_size, void* d_ws, size_t ws_size,
                              hipStream_t stream) {
    const float* x     = (const float*)d_in[0];
    const int*   ei    = (const int*)d_in[1];
    const int*   batch = (const int*)d_in[2];
    const float* W1 = (const float*)d_in[3];  const float* b1 = (const float*)d_in[4];
    const float* W2 = (const float*)d_in[5];  const float* b2 = (const float*)d_in[6];
    const float* W3 = (const float*)d_in[7];  const float* b3 = (const float*)d_in[8];
    const float* Wc = (const float*)d_in[9];  const float* bc = (const float*)d_in[10];
    float* out = (float*)d_out;

    const int* src = ei;
    const int* dst = ei + EE;

    char* w = (char*)d_ws;
    __half* h16     = (__half*)w;  w += (size_t)NN * HH * sizeof(__half);          // 25.6 MB
    __half* t16     = (__half*)w;  w += (size_t)(NN + 1) * HH * sizeof(__half);    // 25.6 MB + zero row
    __half* wt16    = (__half*)w;  w += (size_t)3 * HH * HH * sizeof(__half);
    float*  dinv    = (float*)w;   w += (size_t)NN * sizeof(float);
    int*    csr_src = (int*)w;     w += (size_t)(ETOT + 8) * sizeof(int);          // +pad for 4-slot overread
    int*    staged  = (int*)w;     w += (size_t)EE * sizeof(int);
    int*    mat     = (int*)w;     w += (size_t)MATL * sizeof(int);
    int*    matscan = (int*)w;     w += (size_t)(MATL + 1) * sizeof(int);
    int*    row_off = (int*)w;     w += (size_t)(NN + 1) * sizeof(int);
    int*    counts  = (int*)w;     w += (size_t)NN * sizeof(int);
    float*  pooled  = (float*)w;   w += (size_t)GG * HH * sizeof(float);
    float*  gcnt    = (float*)w;   w += (size_t)GG * sizeof(float);

    // prep
    k_init  <<<(GG * HH + 255) / 256, 256, 0, stream>>>(pooled, gcnt, t16);
    k_prepw <<<3, 256, 0, stream>>>(W1, W2, W3, wt16);

    // CSR build: bucketed two-phase partition
    k_hist      <<<NBLK, 256, 0, stream>>>(dst, mat);
    k_scan1     <<<1, 1024, 0, stream>>>(mat, matscan, MATL, EE);
    k_binscatter<<<NBLK, 256, 0, stream>>>(src, dst, matscan, staged);
    k_bcount    <<<NB, 256, 0, stream>>>(matscan, staged, counts, dinv);
    k_scan1     <<<1, 1024, 0, stream>>>(counts, row_off, NN, ETOT);
    k_place     <<<NB, 256, 0, stream>>>(matscan, staged, row_off, csr_src);

    const int gemm_grid = (NN + 127) / 128;   // 782
    const int agg_grid  = NN * 64 / 256;      // 25000

    // layer 1 (fp32 input staged+converted in-kernel)
    k_gemm<1><<<gemm_grid, 256, 0, stream>>>(x, wt16,                dinv, t16);
    k_agg    <<<agg_grid, 256, 0, stream>>>(t16, h16, row_off, csr_src, dinv, b1, 1);
    // layer 2
    k_gemm<0><<<gemm_grid, 256, 0, stream>>>(h16, wt16 + HH * HH,    dinv, t16);
    k_agg    <<<agg_grid, 256, 0, stream>>>(t16, h16, row_off, csr_src, dinv, b2, 1);
    // layer 3 (no relu)
    k_gemm<0><<<gemm_grid, 256, 0, stream>>>(h16, wt16 + 2 * HH * HH, dinv, t16);
    k_agg    <<<agg_grid, 256, 0, stream>>>(t16, h16, row_off, csr_src, dinv, b3, 0);

    // pool + classify
    k_pool<<<(NN + 63) / 64, 128, 0, stream>>>(h16, batch, pooled, gcnt);
    k_classify<<<(GG * CC + 255) / 256, 256, 0, stream>>>(pooled, gcnt, Wc, bc, out);
}

// Round 8
// 337.722 us; speedup vs baseline: 1.6353x; 1.6353x over previous
//
#include <hip/hip_runtime.h>
#include <hip/hip_fp16.h>

#define NN 100000
#define EE 1600000
#define HH 128
#define GG 64
#define CC 32
#define ETOT (EE + NN)   // edges + self-loops

// bucketed-partition params
#define NB 256                      // dst buckets
#define BS 392                      // nodes per bucket (256*392 >= 100000)
#define CHUNK 8192                  // edges per partition block
#define NBLK ((EE + CHUNK - 1) / CHUNK)   // 196
#define MATL (NB * NBLK)            // 50176

typedef _Float16 half8 __attribute__((ext_vector_type(8)));
typedef float f32x4 __attribute__((ext_vector_type(4)));

// ---------------- init: zero pool accumulators + t16 zero-row (row NN) ----------------
__global__ void k_init(float* __restrict__ pooled, float* __restrict__ gcnt, __half* __restrict__ t16) {
    int i = blockIdx.x * blockDim.x + threadIdx.x;
    if (i < GG * HH) pooled[i] = 0.f;
    if (i < GG) gcnt[i] = 0.f;
    if (i < HH) t16[(size_t)NN * HH + i] = __float2half(0.f);
}

// ---------------- W[k][n] fp32 -> Wt[n][k] fp16 (3 layers) ----------------
__global__ __launch_bounds__(256) void k_prepw(const float* __restrict__ W1, const float* __restrict__ W2,
                                               const float* __restrict__ W3, __half* __restrict__ wt) {
    __shared__ float sW[HH * (HH + 1)];
    const float* W = (blockIdx.x == 0) ? W1 : (blockIdx.x == 1) ? W2 : W3;
    __half* out = wt + (size_t)blockIdx.x * HH * HH;
    int t = threadIdx.x;
    #pragma unroll 4
    for (int i = 0; i < 64; i++) {
        int idx = i * 256 + t;
        sW[(idx >> 7) * (HH + 1) + (idx & 127)] = W[idx];
    }
    __syncthreads();
    #pragma unroll 4
    for (int i = 0; i < 64; i++) {
        int o = i * 256 + t;
        int n = o >> 7, k = o & 127;
        out[o] = __float2half(sW[k * (HH + 1) + n]);
    }
}

// ---------------- generalized 3-phase exclusive scan (multi-block, parallel) ----------------
__global__ __launch_bounds__(1024) void k_psumG(const int* __restrict__ in, int* __restrict__ bsum, int L) {
    __shared__ int red[1024];
    int i = blockIdx.x * 1024 + threadIdx.x;
    red[threadIdx.x] = (i < L) ? in[i] : 0;
    __syncthreads();
    for (int off = 512; off > 0; off >>= 1) {
        if (threadIdx.x < off) red[threadIdx.x] += red[threadIdx.x + off];
        __syncthreads();
    }
    if (threadIdx.x == 0) bsum[blockIdx.x] = red[0];
}
__global__ __launch_bounds__(1024) void k_bscanG(const int* __restrict__ bsum, int* __restrict__ boff, int nb) {
    __shared__ int s[1024];
    int t = threadIdx.x;
    s[t] = (t < nb) ? bsum[t] : 0;
    __syncthreads();
    for (int off = 1; off < 1024; off <<= 1) {
        int tmp = (t >= off) ? s[t - off] : 0;
        __syncthreads();
        s[t] += tmp;
        __syncthreads();
    }
    if (t < nb) boff[t] = s[t] - bsum[t];
}
__global__ __launch_bounds__(1024) void k_localG(const int* __restrict__ in, const int* __restrict__ boff,
                                                 int* __restrict__ off, int L, int total) {
    __shared__ int s[1024];
    int i = blockIdx.x * 1024 + threadIdx.x, t = threadIdx.x;
    int v = (i < L) ? in[i] : 0;
    s[t] = v;
    __syncthreads();
    for (int o = 1; o < 1024; o <<= 1) {
        int tmp = (t >= o) ? s[t - o] : 0;
        __syncthreads();
        s[t] += tmp;
        __syncthreads();
    }
    if (i < L) off[i] = boff[blockIdx.x] + s[t] - v;
    if (i == L - 1) off[L] = total;
}

// ---------------- phase A1: per-block bucket histogram -> mat[bucket][block] ----------------
__global__ __launch_bounds__(256) void k_hist(const int* __restrict__ dst, int* __restrict__ mat) {
    __shared__ int hist[NB];
    int t = threadIdx.x, blk = blockIdx.x;
    hist[t] = 0;
    __syncthreads();
    int base = blk * CHUNK;
    #pragma unroll 4
    for (int it = 0; it < CHUNK / 256; it++) {
        int e = base + it * 256 + t;
        if (e < EE) atomicAdd(&hist[dst[e] / BS], 1);
    }
    __syncthreads();
    mat[t * NBLK + blk] = hist[t];
}

// ---------------- phase A2: scatter edges into per-(block,bucket) runs ----------------
__global__ __launch_bounds__(256) void k_binscatter(const int* __restrict__ src, const int* __restrict__ dst,
                                                    const int* __restrict__ matscan, int* __restrict__ staged) {
    __shared__ int lcur[NB];
    int t = threadIdx.x, blk = blockIdx.x;
    lcur[t] = matscan[t * NBLK + blk];
    __syncthreads();
    int base = blk * CHUNK;
    #pragma unroll 4
    for (int it = 0; it < CHUNK / 256; it++) {
        int e = base + it * 256 + t;
        if (e < EE) {
            int d = dst[e], s = src[e];
            int b = d / BS;
            int pos = atomicAdd(&lcur[b], 1);
            staged[pos] = s | ((d - b * BS) << 17);     // src 17b | dst_local 9b
        }
    }
}

// ---------------- phase B1: per-bucket degree counts (incl self) + dinv ----------------
__global__ __launch_bounds__(256) void k_bcount(const int* __restrict__ matscan, const int* __restrict__ staged,
                                                int* __restrict__ counts, float* __restrict__ dinv) {
    __shared__ int cnt[BS];
    int t = threadIdx.x, b = blockIdx.x;
    for (int i = t; i < BS; i += 256) cnt[i] = 1;       // self-loop
    __syncthreads();
    int beg = matscan[b * NBLK], end = matscan[(b + 1) * NBLK];
    for (int p = beg + t; p < end; p += 256) atomicAdd(&cnt[staged[p] >> 17], 1);
    __syncthreads();
    int nb0 = b * BS;
    for (int i = t; i < BS; i += 256) {
        int n = nb0 + i;
        if (n < NN) { int c = cnt[i]; counts[n] = c; dinv[n] = rsqrtf((float)c); }
    }
}

// ---------------- phase B2: place edges into CSR (L2-local per bucket) ----------------
__global__ __launch_bounds__(256) void k_place(const int* __restrict__ matscan, const int* __restrict__ staged,
                                               const int* __restrict__ row_off, int* __restrict__ csr_src) {
    __shared__ int rof[BS];
    __shared__ int lcur[BS];
    int t = threadIdx.x, b = blockIdx.x;
    int nb0 = b * BS;
    for (int i = t; i < BS; i += 256) {
        int n = nb0 + i;
        int r = (n < NN) ? row_off[n] : 0;
        rof[i] = r; lcur[i] = 1;
        if (n < NN) csr_src[r] = n;                     // self edge in slot 0
    }
    __syncthreads();
    int beg = matscan[b * NBLK], end = matscan[(b + 1) * NBLK];
    for (int p = beg + t; p < end; p += 256) {
        int pk = staged[p];
        int dl = pk >> 17, s = pk & 0x1FFFF;
        int pos = rof[dl] + atomicAdd(&lcur[dl], 1);
        csr_src[pos] = s;
    }
}

// ---------------- MFMA GEMM: T[r][c](fp16) = dinv[r] * (A[r][:] @ W)[c] ----------------
// F32IN: A is fp32 (layer 1, converts during staging); else fp16.
template<int F32IN>
__global__ __launch_bounds__(256) void k_gemm(const void* __restrict__ Ap, const __half* __restrict__ Wt,
                                              const float* __restrict__ dinv, __half* __restrict__ T) {
    __shared__ __align__(16) char sm[64 * 1024];
    char* sA = sm;                 // 128 rows x 256B fp16, XOR-swizzled
    char* sB = sm + 32 * 1024;
    int tid = threadIdx.x;
    int r0 = blockIdx.x * 128;

    #pragma unroll
    for (int it = 0; it < 8; it++) {
        int p = (tid + it * 256) * 16;            // LDS byte (fp16 tile)
        int lrow = p >> 8;
        int grow = r0 + lrow; if (grow > NN - 1) grow = NN - 1;
        uint4 v;
        if (F32IN) {
            const char* Ab = (const char*)Ap;
            const float4* f0 = (const float4*)(Ab + (size_t)grow * 512 + (p & 255) * 2);
            float4 a = f0[0], b = f0[1];
            union { uint4 u; __half2 h[4]; } pk;
            pk.h[0] = __floats2half2_rn(a.x, a.y);
            pk.h[1] = __floats2half2_rn(a.z, a.w);
            pk.h[2] = __floats2half2_rn(b.x, b.y);
            pk.h[3] = __floats2half2_rn(b.z, b.w);
            v = pk.u;
        } else {
            const char* Ab = (const char*)Ap;
            v = *(const uint4*)(Ab + (size_t)grow * 256 + (p & 255));
        }
        *(uint4*)(sA + (p ^ ((lrow & 7) << 4))) = v;
    }
    const char* Wb = (const char*)Wt;
    #pragma unroll
    for (int it = 0; it < 8; it++) {
        int p = (tid + it * 256) * 16;
        int lrow = p >> 8;
        uint4 v = *(const uint4*)(Wb + p);
        *(uint4*)(sB + (p ^ ((lrow & 7) << 4))) = v;
    }
    __syncthreads();

    int w = tid >> 6;
    int lane = tid & 63;
    int q = lane >> 4;
    int ln = lane & 15;
    int wr = (w >> 1) * 64;
    int wc = (w & 1) * 64;

    f32x4 acc[4][4];
    #pragma unroll
    for (int a = 0; a < 4; a++)
        #pragma unroll
        for (int b = 0; b < 4; b++) acc[a][b] = (f32x4)0.f;

    #pragma unroll
    for (int ks = 0; ks < 4; ks++) {
        int koff = ks * 64 + q * 16;
        half8 af[4], bf[4];
        #pragma unroll
        for (int mi = 0; mi < 4; mi++) {
            int row = wr + mi * 16 + ln;
            af[mi] = *(half8*)(sA + row * 256 + (koff ^ ((row & 7) << 4)));
        }
        #pragma unroll
        for (int ni = 0; ni < 4; ni++) {
            int row = wc + ni * 16 + ln;
            bf[ni] = *(half8*)(sB + row * 256 + (koff ^ ((row & 7) << 4)));
        }
        #pragma unroll
        for (int mi = 0; mi < 4; mi++)
            #pragma unroll
            for (int ni = 0; ni < 4; ni++)
                acc[mi][ni] = __builtin_amdgcn_mfma_f32_16x16x32_f16(af[mi], bf[ni], acc[mi][ni], 0, 0, 0);
    }

    float dv[4][4];
    #pragma unroll
    for (int mi = 0; mi < 4; mi++)
        #pragma unroll
        for (int r = 0; r < 4; r++) {
            int grow = r0 + wr + mi * 16 + q * 4 + r;
            dv[mi][r] = dinv[grow < NN ? grow : 0];
        }
    #pragma unroll
    for (int mi = 0; mi < 4; mi++) {
        #pragma unroll
        for (int r = 0; r < 4; r++) {
            int grow = r0 + wr + mi * 16 + q * 4 + r;
            if (grow < NN) {
                #pragma unroll
                for (int ni = 0; ni < 4; ni++) {
                    int gcol = wc + ni * 16 + ln;
                    T[(size_t)grow * HH + gcol] = __float2half(acc[mi][ni][r] * dv[mi][r]);
                }
            }
        }
    }
}

// ---------------- aggregation: O[n] = relu?( dinv[n]*sum_{csr} T'[src] + bias ) ----------------
// 4 edges/wave-iter; packed fp16 accumulate (v_pk_add_f16); zero-row NN for invalid slots.
__global__ __launch_bounds__(256) void k_agg(const __half* __restrict__ T, __half* __restrict__ O,
                                             const int* __restrict__ row_off, const int* __restrict__ csr_src,
                                             const float* __restrict__ dinv,
                                             const float* __restrict__ bias, int relu) {
    int gt = blockIdx.x * blockDim.x + threadIdx.x;
    int n = gt >> 6;
    if (n >= NN) return;
    int lane = threadIdx.x & 63;
    int g  = lane >> 4;
    int li = lane & 15;

    int beg = row_off[n], end = row_off[n + 1];
    int nit = (end - beg + 3) >> 2;

    __half2 acch[4];
    #pragma unroll
    for (int c = 0; c < 4; c++) acch[c] = __floats2half2_rn(0.f, 0.f);

    int p = beg + g;
    const char* Tb = (const char*)T;
    #pragma unroll 4
    for (int i = 0; i < nit; i++, p += 4) {
        int sraw = csr_src[p];                        // csr_src padded by 8 ints
        int s = (p < end) ? sraw : NN;                // zero row for invalid slots
        uint4 raw = *(const uint4*)(Tb + (((unsigned)s << 8) | ((unsigned)li << 4)));
        const __half2* hp = (const __half2*)&raw;
        acch[0] = __hadd2(acch[0], hp[0]);
        acch[1] = __hadd2(acch[1], hp[1]);
        acch[2] = __hadd2(acch[2], hp[2]);
        acch[3] = __hadd2(acch[3], hp[3]);
    }

    // cross-slot reduce in fp16 (lanes l, l^16, l^32, l^48)
    #pragma unroll
    for (int c = 0; c < 4; c++) {
        union { __half2 h; int i; } u, v;
        u.h = acch[c];
        v.i = __shfl_xor(u.i, 16, 64);
        u.h = __hadd2(u.h, v.h);
        v.i = __shfl_xor(u.i, 32, 64);
        u.h = __hadd2(u.h, v.h);
        acch[c] = u.h;
    }

    if (g == 0) {
        float dn = dinv[n];
        float2 f0 = __half22float2(acch[0]);
        float2 f1 = __half22float2(acch[1]);
        float2 f2 = __half22float2(acch[2]);
        float2 f3 = __half22float2(acch[3]);
        const float4* B4 = (const float4*)bias;
        float4 b0 = B4[li * 2], b1 = B4[li * 2 + 1];
        float o0 = dn * f0.x + b0.x, o1 = dn * f0.y + b0.y;
        float o2 = dn * f1.x + b0.z, o3 = dn * f1.y + b0.w;
        float o4 = dn * f2.x + b1.x, o5 = dn * f2.y + b1.y;
        float o6 = dn * f3.x + b1.z, o7 = dn * f3.y + b1.w;
        if (relu) {
            o0 = fmaxf(o0, 0.f); o1 = fmaxf(o1, 0.f); o2 = fmaxf(o2, 0.f); o3 = fmaxf(o3, 0.f);
            o4 = fmaxf(o4, 0.f); o5 = fmaxf(o5, 0.f); o6 = fmaxf(o6, 0.f); o7 = fmaxf(o7, 0.f);
        }
        union { uint4 u; __half2 h2[4]; } pk;
        pk.h2[0] = __floats2half2_rn(o0, o1);
        pk.h2[1] = __floats2half2_rn(o2, o3);
        pk.h2[2] = __floats2half2_rn(o4, o5);
        pk.h2[3] = __floats2half2_rn(o6, o7);
        *(uint4*)(O + (size_t)n * HH + li * 8) = pk.u;
    }
}

// ---------------- pooling: batch sorted -> run-length accumulate (fp16 in) ----------------
__global__ __launch_bounds__(128) void k_pool(const __half* __restrict__ Hm, const int* __restrict__ batch,
                                              float* __restrict__ pooled, float* __restrict__ gcnt) {
    int j = threadIdx.x;
    int n0 = blockIdx.x * 64;
    int nend = n0 + 64; if (nend > NN) nend = NN;
    float acc = 0.f;
    int gcur = batch[n0];
    int run = 0;
    for (int n = n0; n < nend; n++) {
        int g = batch[n];
        if (g != gcur) {
            atomicAdd(&pooled[gcur * HH + j], acc);
            if (j == 0) atomicAdd(&gcnt[gcur], (float)run);
            acc = 0.f; run = 0; gcur = g;
        }
        acc += __half2float(Hm[(size_t)n * HH + j]);
        run++;
    }
    atomicAdd(&pooled[gcur * HH + j], acc);
    if (j == 0) atomicAdd(&gcnt[gcur], (float)run);
}

// ---------------- classifier ----------------
__global__ void k_classify(const float* __restrict__ pooled, const float* __restrict__ gcnt,
                           const float* __restrict__ Wc, const float* __restrict__ bc,
                           float* __restrict__ out) {
    int idx = blockIdx.x * blockDim.x + threadIdx.x;
    if (idx >= GG * CC) return;
    int g = idx >> 5, c = idx & 31;
    float inv = 1.f / fmaxf(gcnt[g], 1.f);
    float acc = bc[c];
    for (int k = 0; k < HH; k++) acc += pooled[g * HH + k] * inv * Wc[k * CC + c];
    out[idx] = acc;
}

extern "C" void kernel_launch(void* const* d_in, const int* in_sizes, int n_in,
                              void* d_out, int out_size, void* d_ws, size_t ws_size,
                              hipStream_t stream) {
    const float* x     = (const float*)d_in[0];
    const int*   ei    = (const int*)d_in[1];
    const int*   batch = (const int*)d_in[2];
    const float* W1 = (const float*)d_in[3];  const float* b1 = (const float*)d_in[4];
    const float* W2 = (const float*)d_in[5];  const float* b2 = (const float*)d_in[6];
    const float* W3 = (const float*)d_in[7];  const float* b3 = (const float*)d_in[8];
    const float* Wc = (const float*)d_in[9];  const float* bc = (const float*)d_in[10];
    float* out = (float*)d_out;

    const int* src = ei;
    const int* dst = ei + EE;

    char* w = (char*)d_ws;
    __half* h16     = (__half*)w;  w += (size_t)NN * HH * sizeof(__half);          // 25.6 MB
    __half* t16     = (__half*)w;  w += (size_t)(NN + 1) * HH * sizeof(__half);    // 25.6 MB + zero row
    __half* wt16    = (__half*)w;  w += (size_t)3 * HH * HH * sizeof(__half);
    float*  dinv    = (float*)w;   w += (size_t)NN * sizeof(float);
    int*    csr_src = (int*)w;     w += (size_t)(ETOT + 8) * sizeof(int);          // +pad for 4-slot overread
    int*    staged  = (int*)w;     w += (size_t)EE * sizeof(int);
    int*    mat     = (int*)w;     w += (size_t)MATL * sizeof(int);
    int*    matscan = (int*)w;     w += (size_t)(MATL + 1) * sizeof(int);
    int*    row_off = (int*)w;     w += (size_t)(NN + 1) * sizeof(int);
    int*    counts  = (int*)w;     w += (size_t)NN * sizeof(int);
    int*    bsum    = (int*)w;     w += (size_t)1024 * sizeof(int);
    int*    boff    = (int*)w;     w += (size_t)1024 * sizeof(int);
    float*  pooled  = (float*)w;   w += (size_t)GG * HH * sizeof(float);
    float*  gcnt    = (float*)w;   w += (size_t)GG * sizeof(float);

    const int matblk = (MATL + 1023) / 1024;   // 49
    const int cntblk = (NN + 1023) / 1024;     // 98

    // prep
    k_init  <<<(GG * HH + 255) / 256, 256, 0, stream>>>(pooled, gcnt, t16);
    k_prepw <<<3, 256, 0, stream>>>(W1, W2, W3, wt16);

    // CSR build: bucketed two-phase partition (multi-block scans)
    k_hist      <<<NBLK, 256, 0, stream>>>(dst, mat);
    k_psumG     <<<matblk, 1024, 0, stream>>>(mat, bsum, MATL);
    k_bscanG    <<<1, 1024, 0, stream>>>(bsum, boff, matblk);
    k_localG    <<<matblk, 1024, 0, stream>>>(mat, boff, matscan, MATL, EE);
    k_binscatter<<<NBLK, 256, 0, stream>>>(src, dst, matscan, staged);
    k_bcount    <<<NB, 256, 0, stream>>>(matscan, staged, counts, dinv);
    k_psumG     <<<cntblk, 1024, 0, stream>>>(counts, bsum, NN);
    k_bscanG    <<<1, 1024, 0, stream>>>(bsum, boff, cntblk);
    k_localG    <<<cntblk, 1024, 0, stream>>>(counts, boff, row_off, NN, ETOT);
    k_place     <<<NB, 256, 0, stream>>>(matscan, staged, row_off, csr_src);

    const int gemm_grid = (NN + 127) / 128;   // 782
    const int agg_grid  = NN * 64 / 256;      // 25000

    // layer 1 (fp32 input staged+converted in-kernel)
    k_gemm<1><<<gemm_grid, 256, 0, stream>>>(x, wt16,                dinv, t16);
    k_agg    <<<agg_grid, 256, 0, stream>>>(t16, h16, row_off, csr_src, dinv, b1, 1);
    // layer 2
    k_gemm<0><<<gemm_grid, 256, 0, stream>>>(h16, wt16 + HH * HH,    dinv, t16);
    k_agg    <<<agg_grid, 256, 0, stream>>>(t16, h16, row_off, csr_src, dinv, b2, 1);
    // layer 3 (no relu)
    k_gemm<0><<<gemm_grid, 256, 0, stream>>>(h16, wt16 + 2 * HH * HH, dinv, t16);
    k_agg    <<<agg_grid, 256, 0, stream>>>(t16, h16, row_off, csr_src, dinv, b3, 0);

    // pool + classify
    k_pool<<<(NN + 63) / 64, 128, 0, stream>>>(h16, batch, pooled, gcnt);
    k_classify<<<(GG * CC + 255) / 256, 256, 0, stream>>>(pooled, gcnt, Wc, bc, out);
}